// Round 1
// baseline (373.558 us; speedup 1.0000x reference)
//
#include <hip/hip_runtime.h>
#include <math.h>

#define BATCH 8
#define CH    64
#define HH    128
#define WW    128
#define HWSZ  (HH * WW)       // 16384
#define COUT  64
#define KTAPS 9
#define OMCH  27              // 3 * KTAPS

// ---------------------------------------------------------------------------
// Kernel 0: transpose w_dcn [co][c][k] -> wT [k][c][co] so the main kernel's
// weight reads are contiguous wave-uniform addresses (=> s_load_dwordx16).
// ---------------------------------------------------------------------------
__global__ void transpose_w_kernel(const float* __restrict__ w_dcn,
                                   float* __restrict__ wT) {
    int tid = blockIdx.x * 256 + threadIdx.x;
    int nthreads = gridDim.x * 256;
    // wT[(k*CH + c)*COUT + co] = w_dcn[co*CH*KTAPS + c*KTAPS + k]
    for (int j = tid; j < KTAPS * CH * COUT; j += nthreads) {
        int co = j & 63;
        int kc = j >> 6;
        int c  = kc & 63;
        int k  = kc >> 6;
        wT[j] = w_dcn[co * (CH * KTAPS) + c * KTAPS + k];
    }
}

// ---------------------------------------------------------------------------
// Kernel 1: offset conv (regular 3x3, pad 1) -> absolute sample coords + mask
// Thread per output pixel; 27 accumulators; weights staged in LDS [c*9+t][28]
// (pad to 28 for float4 alignment; broadcast reads, conflict-free).
// ---------------------------------------------------------------------------
__global__ __launch_bounds__(256) void offset_conv_kernel(
    const float* __restrict__ x, const float* __restrict__ w_off,
    const float* __restrict__ b_off,
    float* __restrict__ py, float* __restrict__ px, float* __restrict__ pm) {
    __shared__ float wl[CH * KTAPS * 28];  // 64*9*28 floats = 64512 B

    for (int j = threadIdx.x; j < CH * KTAPS * 28; j += 256) {
        int ct = j / 28;
        int oc = j - ct * 28;
        wl[j] = (oc < OMCH) ? w_off[oc * (CH * KTAPS) + ct] : 0.f;
    }
    __syncthreads();

    int idx = blockIdx.x * 256 + threadIdx.x;  // b*HWSZ + pix
    int b   = idx >> 14;
    int pix = idx & (HWSZ - 1);
    int ho  = pix >> 7;
    int wo  = pix & (WW - 1);

    float acc[28];
#pragma unroll
    for (int oc = 0; oc < OMCH; ++oc) acc[oc] = b_off[oc];
    acc[27] = 0.f;

    const float* xb = x + (size_t)b * CH * HWSZ;
    int y0 = ho - 1, x0 = wo - 1;
    bool ry[3] = { y0 >= 0, true, ho + 1 < HH };
    bool rx[3] = { x0 >= 0, true, wo + 1 < WW };

    for (int c = 0; c < CH; ++c) {
        const float* xc = xb + c * HWSZ;
        float xv[9];
#pragma unroll
        for (int i = 0; i < 3; ++i) {
#pragma unroll
            for (int j = 0; j < 3; ++j) {
                xv[i * 3 + j] = (ry[i] && rx[j]) ? xc[(y0 + i) * WW + (x0 + j)] : 0.f;
            }
        }
#pragma unroll
        for (int t = 0; t < KTAPS; ++t) {
            const float4* wrow = (const float4*)(&wl[(c * KTAPS + t) * 28]);
            float xt = xv[t];
#pragma unroll
            for (int q = 0; q < 7; ++q) {
                float4 w4 = wrow[q];
                acc[q * 4 + 0] = fmaf(xt, w4.x, acc[q * 4 + 0]);
                acc[q * 4 + 1] = fmaf(xt, w4.y, acc[q * 4 + 1]);
                acc[q * 4 + 2] = fmaf(xt, w4.z, acc[q * 4 + 2]);
                acc[q * 4 + 3] = fmaf(xt, w4.w, acc[q * 4 + 3]);
            }
        }
    }

    // Epilogue: absolute sample coordinates + sigmoid mask
#pragma unroll
    for (int t = 0; t < KTAPS; ++t) {
        int ky = t / 3, kx = t - ky * 3;
        float vy = acc[t]      + (float)(ho - 1 + ky);   // base_y + ky*DIL
        float vx = acc[9 + t]  + (float)(wo - 1 + kx);
        float vm = 1.f / (1.f + __expf(-acc[18 + t]));
        int o = ((b * KTAPS + t) * HWSZ) + pix;
        py[o] = vy;
        px[o] = vx;
        pm[o] = vm;
    }
}

// ---------------------------------------------------------------------------
// Kernel 2: deformable gather + 64x576 matvec per pixel.
// Thread per pixel, 64 accumulators. Weights read via wave-uniform contiguous
// addresses (wT[k][c][co]) -> scalar loads, SGPR operand in v_fmac_f32.
// ---------------------------------------------------------------------------
__global__ __launch_bounds__(256) void dcn_main_kernel(
    const float* __restrict__ x, const float* __restrict__ wT,
    const float* __restrict__ b_dcn, const float* __restrict__ py,
    const float* __restrict__ px, const float* __restrict__ pm,
    float* __restrict__ out) {
    int idx = blockIdx.x * 256 + threadIdx.x;
    int b   = idx >> 14;
    int pix = idx & (HWSZ - 1);

    float acc[COUT];
#pragma unroll
    for (int co = 0; co < COUT; ++co) acc[co] = b_dcn[co];

    const float* xb = x + (size_t)b * CH * HWSZ;

    for (int k = 0; k < KTAPS; ++k) {
        int o = ((b * KTAPS + k) * HWSZ) + pix;
        float fy = py[o], fx = px[o], m = pm[o];
        float y0f = floorf(fy), x0f = floorf(fx);
        float dy = fy - y0f, dx = fx - x0f;
        int y0 = (int)y0f, x0i = (int)x0f;
        int y1 = y0 + 1, x1 = x0i + 1;
        bool vy0 = (y0 >= 0) & (y0 < HH);
        bool vy1 = (y1 >= 0) & (y1 < HH);
        bool vx0 = (x0i >= 0) & (x0i < WW);
        bool vx1 = (x1 >= 0) & (x1 < WW);
        float w00 = (1.f - dy) * (1.f - dx) * m; if (!(vy0 && vx0)) w00 = 0.f;
        float w01 = (1.f - dy) * dx * m;         if (!(vy0 && vx1)) w01 = 0.f;
        float w10 = dy * (1.f - dx) * m;         if (!(vy1 && vx0)) w10 = 0.f;
        float w11 = dy * dx * m;                 if (!(vy1 && vx1)) w11 = 0.f;
        int yc0 = min(max(y0, 0), HH - 1), yc1 = min(max(y1, 0), HH - 1);
        int xc0 = min(max(x0i, 0), WW - 1), xc1 = min(max(x1, 0), WW - 1);
        int i00 = yc0 * WW + xc0, i01 = yc0 * WW + xc1;
        int i10 = yc1 * WW + xc0, i11 = yc1 * WW + xc1;

        const float* wk = wT + k * CH * COUT;
#pragma unroll 2
        for (int c = 0; c < CH; ++c) {
            const float* xc = xb + c * HWSZ;
            float v00 = xc[i00], v01 = xc[i01], v10 = xc[i10], v11 = xc[i11];
            float col = w00 * v00;
            col = fmaf(w01, v01, col);
            col = fmaf(w10, v10, col);
            col = fmaf(w11, v11, col);
            const float* wr = wk + c * COUT;  // wave-uniform, contiguous
#pragma unroll
            for (int co = 0; co < COUT; ++co)
                acc[co] = fmaf(col, wr[co], acc[co]);
        }
    }

    float* ob = out + (size_t)b * COUT * HWSZ + pix;
#pragma unroll
    for (int co = 0; co < COUT; ++co) ob[co * HWSZ] = acc[co];
}

// ---------------------------------------------------------------------------
extern "C" void kernel_launch(void* const* d_in, const int* in_sizes, int n_in,
                              void* d_out, int out_size, void* d_ws, size_t ws_size,
                              hipStream_t stream) {
    const float* x     = (const float*)d_in[0];
    const float* w_off = (const float*)d_in[1];
    const float* b_off = (const float*)d_in[2];
    const float* w_dcn = (const float*)d_in[3];
    const float* b_dcn = (const float*)d_in[4];
    float* out = (float*)d_out;

    // ws layout (floats): py | px | pm | wT
    const int NOFF = BATCH * KTAPS * HWSZ;  // 1,179,648
    float* ws = (float*)d_ws;
    float* py = ws;
    float* px = py + NOFF;
    float* pm = px + NOFF;
    float* wT = pm + NOFF;                  // 36,864 floats

    hipLaunchKernelGGL(transpose_w_kernel, dim3(36), dim3(256), 0, stream,
                       w_dcn, wT);
    hipLaunchKernelGGL(offset_conv_kernel, dim3(BATCH * HWSZ / 256), dim3(256),
                       0, stream, x, w_off, b_off, py, px, pm);
    hipLaunchKernelGGL(dcn_main_kernel, dim3(BATCH * HWSZ / 256), dim3(256),
                       0, stream, x, wT, b_dcn, py, px, pm, out);
}

// Round 2
// 321.855 us; speedup vs baseline: 1.1606x; 1.1606x over previous
//
#include <hip/hip_runtime.h>
#include <math.h>

#define BATCH 8
#define CH    64
#define HH    128
#define WW    128
#define HWSZ  (HH * WW)       // 16384
#define COUT  64
#define KTAPS 9
#define KDIM  576             // CH * KTAPS
#define LSTR  40              // LDS row stride in ushorts (80 B)

typedef __attribute__((ext_vector_type(8))) short short8;
typedef __attribute__((ext_vector_type(4))) float f32x4;

__device__ __forceinline__ unsigned short f2bf(float f) {
    unsigned int u = __float_as_uint(f);
    u += 0x7fffu + ((u >> 16) & 1u);
    return (unsigned short)(u >> 16);
}

// ---------------------------------------------------------------------------
// Kernel 0: weight prep.
//  wbf [co][ck=k*64+c] bf16  (64 x 576)   for main conv
//  wobf[co][ck=t*64+c] bf16  (32 x 576)   for offset conv (rows 27..31 = 0)
// ---------------------------------------------------------------------------
__global__ void prep_w_kernel(const float* __restrict__ w_dcn,
                              const float* __restrict__ w_off,
                              unsigned short* __restrict__ wbf,
                              unsigned short* __restrict__ wobf) {
    int tid = blockIdx.x * 256 + threadIdx.x;
    const int N1 = COUT * KDIM;      // 36864
    const int N2 = 32 * KDIM;        // 18432
    if (tid < N1) {
        int co = tid / KDIM;
        int ck = tid - co * KDIM;
        int k = ck >> 6, c = ck & 63;
        wbf[tid] = f2bf(w_dcn[(co * CH + c) * KTAPS + k]);
    } else if (tid < N1 + N2) {
        int j = tid - N1;
        int co = j / KDIM;
        int ck = j - co * KDIM;
        int k = ck >> 6, c = ck & 63;
        wobf[j] = (co < 27) ? f2bf(w_off[(co * CH + c) * KTAPS + k]) : 0;
    }
}

// ---------------------------------------------------------------------------
// Kernel 1: offset conv as bf16 MFMA GEMM.
// Block = 64 px, om tile 32co x 64px. K = 576 in 18 chunks (tap k, 32 ch).
// Epilogue converts om -> absolute coords + sigmoid mask.
// ---------------------------------------------------------------------------
__global__ __launch_bounds__(256) void offset_conv_mfma(
    const float* __restrict__ x, const unsigned short* __restrict__ wobf,
    const float* __restrict__ b_off,
    float* __restrict__ opy, float* __restrict__ opx, float* __restrict__ opm) {
    __shared__ unsigned short colL[64 * LSTR];  // 5120 B

    int tid = threadIdx.x;
    int bid = blockIdx.x;
    int b = bid & 7;                 // batch -> XCD pinning
    int pxbase = (bid >> 3) * 64;
    int lane = tid & 63;
    int wv = tid >> 6;               // wave 0..3
    int quad = lane >> 4;
    int n16 = lane & 15;

    int pxl = lane;                  // px for col build
    int cg = wv;                     // c-group 0..3 (8 ch each)
    int pix = pxbase + pxl;
    int ho = pix >> 7, wo = pix & (WW - 1);

    const float* xb = x + (size_t)b * CH * HWSZ;

    f32x4 acc[2] = {{0, 0, 0, 0}, {0, 0, 0, 0}};

    for (int q = 0; q < 18; ++q) {
        int k = q >> 1;
        int cbase = (q & 1) * 32;
        int ky = k / 3, kx = k - ky * 3;
        int yy = ho + ky - 1, xx = wo + kx - 1;
        bool v = (yy >= 0) & (yy < HH) & (xx >= 0) & (xx < WW);
        int idx = v ? (yy * WW + xx) : 0;
        const float* xc = xb + (size_t)(cbase + cg * 8) * HWSZ + idx;

        unsigned short col8[8];
#pragma unroll
        for (int j = 0; j < 8; ++j) {
            float val = xc[(size_t)j * HWSZ];
            col8[j] = v ? f2bf(val) : (unsigned short)0;
        }
        __syncthreads();
        *(uint4*)(&colL[pxl * LSTR + cg * 8]) = *(const uint4*)col8;
        __syncthreads();

        int co = (wv & 1) * 16 + n16;
        short8 afrag = *(const short8*)(wobf + co * KDIM + q * 32 + quad * 8);
#pragma unroll
        for (int pt = 0; pt < 2; ++pt) {
            int px_t = (wv >> 1) * 32 + pt * 16 + n16;
            short8 bfrag = *(const short8*)(&colL[px_t * LSTR + quad * 8]);
            acc[pt] = __builtin_amdgcn_mfma_f32_16x16x32_bf16(afrag, bfrag,
                                                              acc[pt], 0, 0, 0);
        }
    }

    // Epilogue: om rows 0..8=oy, 9..17=ox, 18..26=mask
#pragma unroll
    for (int pt = 0; pt < 2; ++pt) {
        int pix2 = pxbase + (wv >> 1) * 32 + pt * 16 + n16;
        int ho2 = pix2 >> 7, wo2 = pix2 & (WW - 1);
#pragma unroll
        for (int r = 0; r < 4; ++r) {
            int co = (wv & 1) * 16 + quad * 4 + r;
            if (co >= 27) continue;
            float val = acc[pt][r] + b_off[co];
            if (co < 9) {
                int t = co;
                opy[((b * KTAPS + t) * HWSZ) + pix2] = val + (float)(ho2 - 1 + t / 3);
            } else if (co < 18) {
                int t = co - 9;
                opx[((b * KTAPS + t) * HWSZ) + pix2] = val + (float)(wo2 - 1 + t % 3);
            } else {
                int t = co - 18;
                opm[((b * KTAPS + t) * HWSZ) + pix2] = 1.f / (1.f + expf(-val));
            }
        }
    }
}

// ---------------------------------------------------------------------------
// Kernel 2: deformable col build + bf16 MFMA GEMM.
// Block = 64 px, out tile 64co x 64px. Wave w: co range w*16, 4 px tiles.
// ---------------------------------------------------------------------------
__global__ __launch_bounds__(256) void dcn_main_mfma(
    const float* __restrict__ x, const unsigned short* __restrict__ wbf,
    const float* __restrict__ b_dcn, const float* __restrict__ opy,
    const float* __restrict__ opx, const float* __restrict__ opm,
    float* __restrict__ out) {
    __shared__ unsigned short colL[64 * LSTR];  // 5120 B

    int tid = threadIdx.x;
    int bid = blockIdx.x;
    int b = bid & 7;                 // batch -> XCD pinning
    int pxbase = (bid >> 3) * 64;
    int lane = tid & 63;
    int wv = tid >> 6;
    int quad = lane >> 4;
    int n16 = lane & 15;

    int pxl = lane;
    int cg = wv;

    const float* xb = x + (size_t)b * CH * HWSZ;

    f32x4 acc[4] = {{0, 0, 0, 0}, {0, 0, 0, 0}, {0, 0, 0, 0}, {0, 0, 0, 0}};

    for (int q = 0; q < 18; ++q) {
        int k = q >> 1;
        int cbase = (q & 1) * 32;

        // --- bilinear params for (k, px), reused across 8 channels ---
        int o = ((b * KTAPS + k) * HWSZ) + pxbase + pxl;
        float fy = opy[o], fx = opx[o], m = opm[o];
        float y0f = floorf(fy), x0f = floorf(fx);
        float dy = fy - y0f, dx = fx - x0f;
        int y0 = (int)y0f, x0i = (int)x0f;
        int y1 = y0 + 1, x1 = x0i + 1;
        bool vy0 = (y0 >= 0) & (y0 < HH);
        bool vy1 = (y1 >= 0) & (y1 < HH);
        bool vx0 = (x0i >= 0) & (x0i < WW);
        bool vx1 = (x1 >= 0) & (x1 < WW);
        float w00 = (1.f - dy) * (1.f - dx) * m; if (!(vy0 && vx0)) w00 = 0.f;
        float w01 = (1.f - dy) * dx * m;         if (!(vy0 && vx1)) w01 = 0.f;
        float w10 = dy * (1.f - dx) * m;         if (!(vy1 && vx0)) w10 = 0.f;
        float w11 = dy * dx * m;                 if (!(vy1 && vx1)) w11 = 0.f;
        int yc0 = min(max(y0, 0), HH - 1), yc1 = min(max(y1, 0), HH - 1);
        int xc0 = min(max(x0i, 0), WW - 1), xc1 = min(max(x1, 0), WW - 1);
        int i00 = yc0 * WW + xc0, i01 = yc0 * WW + xc1;
        int i10 = yc1 * WW + xc0, i11 = yc1 * WW + xc1;

        const float* xc = xb + (size_t)(cbase + cg * 8) * HWSZ;
        unsigned short col8[8];
#pragma unroll
        for (int j = 0; j < 8; ++j) {
            float v00 = xc[i00], v01 = xc[i01], v10 = xc[i10], v11 = xc[i11];
            float col = w00 * v00;
            col = fmaf(w01, v01, col);
            col = fmaf(w10, v10, col);
            col = fmaf(w11, v11, col);
            col8[j] = f2bf(col);
            xc += HWSZ;
        }
        __syncthreads();
        *(uint4*)(&colL[pxl * LSTR + cg * 8]) = *(const uint4*)col8;
        __syncthreads();

        int co = wv * 16 + n16;
        short8 afrag = *(const short8*)(wbf + co * KDIM + q * 32 + quad * 8);
#pragma unroll
        for (int pt = 0; pt < 4; ++pt) {
            short8 bfrag = *(const short8*)(&colL[(pt * 16 + n16) * LSTR + quad * 8]);
            acc[pt] = __builtin_amdgcn_mfma_f32_16x16x32_bf16(afrag, bfrag,
                                                              acc[pt], 0, 0, 0);
        }
    }

    // Epilogue: D[m = quad*4+r][n = lane&15], co = wv*16 + m
    float* ob = out + (size_t)b * COUT * HWSZ;
#pragma unroll
    for (int pt = 0; pt < 4; ++pt) {
        int px = pxbase + pt * 16 + n16;
#pragma unroll
        for (int r = 0; r < 4; ++r) {
            int co = wv * 16 + quad * 4 + r;
            ob[(size_t)co * HWSZ + px] = acc[pt][r] + b_dcn[co];
        }
    }
}

// ---------------------------------------------------------------------------
extern "C" void kernel_launch(void* const* d_in, const int* in_sizes, int n_in,
                              void* d_out, int out_size, void* d_ws, size_t ws_size,
                              hipStream_t stream) {
    const float* x     = (const float*)d_in[0];
    const float* w_off = (const float*)d_in[1];
    const float* b_off = (const float*)d_in[2];
    const float* w_dcn = (const float*)d_in[3];
    const float* b_dcn = (const float*)d_in[4];
    float* out = (float*)d_out;

    // ws layout: opy | opx | opm (floats) then wbf | wobf (ushorts)
    const int NOFF = BATCH * KTAPS * HWSZ;  // 1,179,648
    float* ws = (float*)d_ws;
    float* opy = ws;
    float* opx = opy + NOFF;
    float* opm = opx + NOFF;
    unsigned short* wbf  = (unsigned short*)(opm + NOFF);
    unsigned short* wobf = wbf + COUT * KDIM;

    hipLaunchKernelGGL(prep_w_kernel, dim3(216), dim3(256), 0, stream,
                       w_dcn, w_off, wbf, wobf);
    hipLaunchKernelGGL(offset_conv_mfma, dim3(BATCH * HWSZ / 64), dim3(256),
                       0, stream, x, wobf, b_off, opy, opx, opm);
    hipLaunchKernelGGL(dcn_main_mfma, dim3(BATCH * HWSZ / 64), dim3(256),
                       0, stream, x, wbf, b_dcn, opy, opx, opm, out);
}

// Round 3
// 216.002 us; speedup vs baseline: 1.7294x; 1.4901x over previous
//
#include <hip/hip_runtime.h>
#include <math.h>

#define BATCH 8
#define CH    64
#define HH    128
#define WW    128
#define HWSZ  (HH * WW)       // 16384
#define COUT  64
#define KTAPS 9
#define KDIM  576             // CH * KTAPS
#define LSTR  72              // ushorts per LDS px-row (144 B = 36 dwords -> max 2-way bank alias, free)

typedef __attribute__((ext_vector_type(8))) short short8;
typedef __attribute__((ext_vector_type(4))) float f32x4;

__device__ __forceinline__ unsigned short f2bf(float f) {
    unsigned int u = __float_as_uint(f);
    u += 0x7fffu + ((u >> 16) & 1u);
    return (unsigned short)(u >> 16);
}
__device__ __forceinline__ float bflo(unsigned int u) { return __uint_as_float(u << 16); }
__device__ __forceinline__ float bfhi(unsigned int u) { return __uint_as_float(u & 0xffff0000u); }

// ---------------------------------------------------------------------------
// Kernel 0: weight prep.
//  wbf [co][ck=k*64+c] bf16  (64 x 576)   main conv
//  wobf[co][ck=k*64+c] bf16  (32 x 576)   offset conv (rows 27..31 = 0)
// ---------------------------------------------------------------------------
__global__ void prep_w_kernel(const float* __restrict__ w_dcn,
                              const float* __restrict__ w_off,
                              unsigned short* __restrict__ wbf,
                              unsigned short* __restrict__ wobf) {
    int tid = blockIdx.x * 256 + threadIdx.x;
    const int N1 = COUT * KDIM;      // 36864
    const int N2 = 32 * KDIM;        // 18432
    if (tid < N1) {
        int co = tid / KDIM;
        int ck = tid - co * KDIM;
        int k = ck >> 6, c = ck & 63;
        wbf[tid] = f2bf(w_dcn[(co * CH + c) * KTAPS + k]);
    } else if (tid < N1 + N2) {
        int j = tid - N1;
        int co = j / KDIM;
        int ck = j - co * KDIM;
        int k = ck >> 6, c = ck & 63;
        wobf[j] = (co < 27) ? f2bf(w_off[(co * CH + c) * KTAPS + k]) : 0;
    }
}

// ---------------------------------------------------------------------------
// Kernel 1: x [b][c][y][x] fp32 -> xt [b][y*W+x][c] bf16 (NHWC, 128 B/pixel)
// LDS tile transpose: coalesced reads AND coalesced 32 B writes.
// ---------------------------------------------------------------------------
__global__ __launch_bounds__(256) void transpose_x_kernel(
    const float* __restrict__ x, unsigned short* __restrict__ xt) {
    __shared__ unsigned short t[64 * LSTR];
    int tid = threadIdx.x, bid = blockIdx.x;
    int b = bid >> 8;
    int pxbase = (bid & 255) * 64;
    int lane = tid & 63, wv = tid >> 6;
    const float* xb = x + (size_t)b * CH * HWSZ + pxbase;
#pragma unroll
    for (int i = 0; i < 16; ++i) {
        int c = wv * 16 + i;
        t[lane * LSTR + c] = f2bf(xb[(size_t)c * HWSZ + lane]);
    }
    __syncthreads();
    int px = tid >> 2, cp = (tid & 3) * 16;
    uint4 q0 = *(const uint4*)&t[px * LSTR + cp];
    uint4 q1 = *(const uint4*)&t[px * LSTR + cp + 8];
    unsigned short* o = xt + (size_t)(b * HWSZ + pxbase + px) * 64 + cp;
    *(uint4*)o = q0;
    *(uint4*)(o + 8) = q1;
}

// ---------------------------------------------------------------------------
// Kernel 2: offset conv as bf16 MFMA GEMM over NHWC x.
// Per tap: 2 dwordx4 loads/thread (16 ch), straight bf16 copy into LDS.
// ---------------------------------------------------------------------------
__global__ __launch_bounds__(256) void offset_conv_mfma(
    const unsigned short* __restrict__ xt, const unsigned short* __restrict__ wobf,
    const float* __restrict__ b_off,
    float* __restrict__ opy, float* __restrict__ opx, float* __restrict__ opm) {
    __shared__ unsigned short colL[64 * LSTR];

    int tid = threadIdx.x, bid = blockIdx.x;
    int b = bid & 7;
    int pxbase = (bid >> 3) * 64;
    int lane = tid & 63, wv = tid >> 6;
    int quad = lane >> 4, n16 = lane & 15;

    int pix = pxbase + lane;
    int ho = pix >> 7, wo = pix & (WW - 1);
    const unsigned short* xb = xt + (size_t)b * HWSZ * 64;
    int cb = wv * 16;

    f32x4 acc[2] = {{0, 0, 0, 0}, {0, 0, 0, 0}};

    for (int k = 0; k < KTAPS; ++k) {
        int ky = k / 3, kx = k - ky * 3;
        int yy = ho + ky - 1, xx = wo + kx - 1;
        bool v = (yy >= 0) & (yy < HH) & (xx >= 0) & (xx < WW);
        int idx = v ? (yy * WW + xx) : 0;
        const uint4* p = (const uint4*)(xb + (size_t)idx * 64 + cb);
        uint4 q0 = p[0], q1 = p[1];
        if (!v) { q0.x = q0.y = q0.z = q0.w = 0; q1 = q0; }

        __syncthreads();
        *(uint4*)&colL[lane * LSTR + cb] = q0;
        *(uint4*)&colL[lane * LSTR + cb + 8] = q1;
        __syncthreads();

        int co = (wv & 1) * 16 + n16;
#pragma unroll
        for (int h = 0; h < 2; ++h) {
            short8 afrag = *(const short8*)(wobf + co * KDIM + k * 64 + h * 32 + quad * 8);
#pragma unroll
            for (int pt = 0; pt < 2; ++pt) {
                int pxt = (wv >> 1) * 32 + pt * 16 + n16;
                short8 bfrag = *(const short8*)(&colL[pxt * LSTR + h * 32 + quad * 8]);
                acc[pt] = __builtin_amdgcn_mfma_f32_16x16x32_bf16(afrag, bfrag,
                                                                  acc[pt], 0, 0, 0);
            }
        }
    }

    // Epilogue: om rows 0..8=oy, 9..17=ox, 18..26=mask
#pragma unroll
    for (int pt = 0; pt < 2; ++pt) {
        int pix2 = pxbase + (wv >> 1) * 32 + pt * 16 + n16;
        int ho2 = pix2 >> 7, wo2 = pix2 & (WW - 1);
#pragma unroll
        for (int r = 0; r < 4; ++r) {
            int co = (wv & 1) * 16 + quad * 4 + r;
            if (co >= 27) continue;
            float val = acc[pt][r] + b_off[co];
            if (co < 9) {
                int t = co;
                opy[((b * KTAPS + t) * HWSZ) + pix2] = val + (float)(ho2 - 1 + t / 3);
            } else if (co < 18) {
                int t = co - 9;
                opx[((b * KTAPS + t) * HWSZ) + pix2] = val + (float)(wo2 - 1 + t % 3);
            } else {
                int t = co - 18;
                opm[((b * KTAPS + t) * HWSZ) + pix2] = 1.f / (1.f + expf(-val));
            }
        }
    }
}

// ---------------------------------------------------------------------------
// Kernel 3: deformable col build (NHWC bf16 gather, 16 ch per dwordx4 pair)
// + bf16 MFMA GEMM. Out tile 64co x 64px per block.
// ---------------------------------------------------------------------------
__global__ __launch_bounds__(256) void dcn_main_mfma(
    const unsigned short* __restrict__ xt, const unsigned short* __restrict__ wbf,
    const float* __restrict__ b_dcn, const float* __restrict__ opy,
    const float* __restrict__ opx, const float* __restrict__ opm,
    float* __restrict__ out) {
    __shared__ unsigned short colL[64 * LSTR];

    int tid = threadIdx.x, bid = blockIdx.x;
    int b = bid & 7;
    int pxbase = (bid >> 3) * 64;
    int lane = tid & 63, wv = tid >> 6;
    int quad = lane >> 4, n16 = lane & 15;

    const unsigned short* xb = xt + (size_t)b * HWSZ * 64;
    int cb = wv * 16;

    f32x4 acc[4] = {{0, 0, 0, 0}, {0, 0, 0, 0}, {0, 0, 0, 0}, {0, 0, 0, 0}};

    for (int k = 0; k < KTAPS; ++k) {
        // bilinear params for (k, px=lane)
        int o = ((b * KTAPS + k) * HWSZ) + pxbase + lane;
        float fy = opy[o], fx = opx[o], m = opm[o];
        float y0f = floorf(fy), x0f = floorf(fx);
        float dy = fy - y0f, dx = fx - x0f;
        int y0 = (int)y0f, x0i = (int)x0f;
        int y1 = y0 + 1, x1 = x0i + 1;
        bool vy0 = (y0 >= 0) & (y0 < HH);
        bool vy1 = (y1 >= 0) & (y1 < HH);
        bool vx0 = (x0i >= 0) & (x0i < WW);
        bool vx1 = (x1 >= 0) & (x1 < WW);
        float w00 = (1.f - dy) * (1.f - dx) * m; if (!(vy0 && vx0)) w00 = 0.f;
        float w01 = (1.f - dy) * dx * m;         if (!(vy0 && vx1)) w01 = 0.f;
        float w10 = dy * (1.f - dx) * m;         if (!(vy1 && vx0)) w10 = 0.f;
        float w11 = dy * dx * m;                 if (!(vy1 && vx1)) w11 = 0.f;
        int yc0 = min(max(y0, 0), HH - 1), yc1 = min(max(y1, 0), HH - 1);
        int xc0 = min(max(x0i, 0), WW - 1), xc1 = min(max(x1, 0), WW - 1);
        int i00 = yc0 * WW + xc0, i01 = yc0 * WW + xc1;
        int i10 = yc1 * WW + xc0, i11 = yc1 * WW + xc1;

        // gather 16 channels x 4 corners (2 dwordx4 each)
        unsigned int va[8], vb[8], vc[8], vd[8];
        {
            const uint4* p00 = (const uint4*)(xb + (size_t)i00 * 64 + cb);
            const uint4* p01 = (const uint4*)(xb + (size_t)i01 * 64 + cb);
            const uint4* p10 = (const uint4*)(xb + (size_t)i10 * 64 + cb);
            const uint4* p11 = (const uint4*)(xb + (size_t)i11 * 64 + cb);
            *(uint4*)&va[0] = p00[0]; *(uint4*)&va[4] = p00[1];
            *(uint4*)&vb[0] = p01[0]; *(uint4*)&vb[4] = p01[1];
            *(uint4*)&vc[0] = p10[0]; *(uint4*)&vc[4] = p10[1];
            *(uint4*)&vd[0] = p11[0]; *(uint4*)&vd[4] = p11[1];
        }
        unsigned int packed[8];
#pragma unroll
        for (int e = 0; e < 8; ++e) {
            float lo = w00 * bflo(va[e]);
            lo = fmaf(w01, bflo(vb[e]), lo);
            lo = fmaf(w10, bflo(vc[e]), lo);
            lo = fmaf(w11, bflo(vd[e]), lo);
            float hi = w00 * bfhi(va[e]);
            hi = fmaf(w01, bfhi(vb[e]), hi);
            hi = fmaf(w10, bfhi(vc[e]), hi);
            hi = fmaf(w11, bfhi(vd[e]), hi);
            packed[e] = (unsigned int)f2bf(lo) | ((unsigned int)f2bf(hi) << 16);
        }

        __syncthreads();
        *(uint4*)&colL[lane * LSTR + cb] = *(const uint4*)&packed[0];
        *(uint4*)&colL[lane * LSTR + cb + 8] = *(const uint4*)&packed[4];
        __syncthreads();

        int co = wv * 16 + n16;
#pragma unroll
        for (int h = 0; h < 2; ++h) {
            short8 afrag = *(const short8*)(wbf + co * KDIM + k * 64 + h * 32 + quad * 8);
#pragma unroll
            for (int pt = 0; pt < 4; ++pt) {
                short8 bfrag = *(const short8*)(&colL[(pt * 16 + n16) * LSTR + h * 32 + quad * 8]);
                acc[pt] = __builtin_amdgcn_mfma_f32_16x16x32_bf16(afrag, bfrag,
                                                                  acc[pt], 0, 0, 0);
            }
        }
    }

    // Epilogue: D[m = quad*4+r][n = lane&15], co = wv*16 + m
    float* ob = out + (size_t)b * COUT * HWSZ;
#pragma unroll
    for (int pt = 0; pt < 4; ++pt) {
        int px = pxbase + pt * 16 + n16;
#pragma unroll
        for (int r = 0; r < 4; ++r) {
            int co = wv * 16 + quad * 4 + r;
            ob[(size_t)co * HWSZ + px] = acc[pt][r] + b_dcn[co];
        }
    }
}

// ---------------------------------------------------------------------------
extern "C" void kernel_launch(void* const* d_in, const int* in_sizes, int n_in,
                              void* d_out, int out_size, void* d_ws, size_t ws_size,
                              hipStream_t stream) {
    const float* x     = (const float*)d_in[0];
    const float* w_off = (const float*)d_in[1];
    const float* b_off = (const float*)d_in[2];
    const float* w_dcn = (const float*)d_in[3];
    const float* b_dcn = (const float*)d_in[4];
    float* out = (float*)d_out;

    // ws layout: xt (bf16 NHWC) | opy | opx | opm (fp32) | wbf | wobf (bf16)
    const int NOFF = BATCH * KTAPS * HWSZ;           // 1,179,648 floats
    unsigned short* xt = (unsigned short*)d_ws;      // 8,388,608 ushorts
    float* opy = (float*)(xt + (size_t)BATCH * HWSZ * 64);
    float* opx = opy + NOFF;
    float* opm = opx + NOFF;
    unsigned short* wbf  = (unsigned short*)(opm + NOFF);
    unsigned short* wobf = wbf + COUT * KDIM;

    hipLaunchKernelGGL(prep_w_kernel, dim3(216), dim3(256), 0, stream,
                       w_dcn, w_off, wbf, wobf);
    hipLaunchKernelGGL(transpose_x_kernel, dim3(2048), dim3(256), 0, stream, x, xt);
    hipLaunchKernelGGL(offset_conv_mfma, dim3(BATCH * HWSZ / 64), dim3(256),
                       0, stream, xt, wobf, b_off, opy, opx, opm);
    hipLaunchKernelGGL(dcn_main_mfma, dim3(BATCH * HWSZ / 64), dim3(256),
                       0, stream, xt, wbf, b_dcn, opy, opx, opm, out);
}

// Round 4
// 189.577 us; speedup vs baseline: 1.9705x; 1.1394x over previous
//
#include <hip/hip_runtime.h>
#include <math.h>

#define BATCH 8
#define CH    64
#define HH    128
#define WW    128
#define HWSZ  (HH * WW)       // 16384
#define COUT  64
#define KTAPS 9
#define KDIM  576             // CH * KTAPS
#define LSTR  72              // ushorts per LDS px-row (144 B)

typedef __attribute__((ext_vector_type(8))) short short8;
typedef __attribute__((ext_vector_type(4))) float f32x4;

__device__ __forceinline__ unsigned short f2bf(float f) {
    unsigned int u = __float_as_uint(f);
    u += 0x7fffu + ((u >> 16) & 1u);
    return (unsigned short)(u >> 16);
}
__device__ __forceinline__ float bflo(unsigned int u) { return __uint_as_float(u << 16); }
__device__ __forceinline__ float bfhi(unsigned int u) { return __uint_as_float(u & 0xffff0000u); }

// bilinear-combine one dword (2 bf16 channels) from 4 corners
__device__ __forceinline__ unsigned int bilin2(unsigned int a, unsigned int b,
                                               unsigned int c, unsigned int d,
                                               float w00, float w01, float w10, float w11) {
    float lo = w00 * bflo(a);
    lo = fmaf(w01, bflo(b), lo);
    lo = fmaf(w10, bflo(c), lo);
    lo = fmaf(w11, bflo(d), lo);
    float hi = w00 * bfhi(a);
    hi = fmaf(w01, bfhi(b), hi);
    hi = fmaf(w10, bfhi(c), hi);
    hi = fmaf(w11, bfhi(d), hi);
    return (unsigned int)f2bf(lo) | ((unsigned int)f2bf(hi) << 16);
}

// ---------------------------------------------------------------------------
// Kernel 0: weight prep.
//  wbf [co][ck=k*64+c] bf16  (64 x 576)   main conv
//  wobf[co][ck=k*64+c] bf16  (32 x 576)   offset conv (rows 27..31 = 0)
// ---------------------------------------------------------------------------
__global__ void prep_w_kernel(const float* __restrict__ w_dcn,
                              const float* __restrict__ w_off,
                              unsigned short* __restrict__ wbf,
                              unsigned short* __restrict__ wobf) {
    int tid = blockIdx.x * 256 + threadIdx.x;
    const int N1 = COUT * KDIM;      // 36864
    const int N2 = 32 * KDIM;        // 18432
    if (tid < N1) {
        int co = tid / KDIM;
        int ck = tid - co * KDIM;
        int k = ck >> 6, c = ck & 63;
        wbf[tid] = f2bf(w_dcn[(co * CH + c) * KTAPS + k]);
    } else if (tid < N1 + N2) {
        int j = tid - N1;
        int co = j / KDIM;
        int ck = j - co * KDIM;
        int k = ck >> 6, c = ck & 63;
        wobf[j] = (co < 27) ? f2bf(w_off[(co * CH + c) * KTAPS + k]) : 0;
    }
}

// ---------------------------------------------------------------------------
// Kernel 1: x [b][c][y][x] fp32 -> xt [b][y*W+x][c] bf16 (NHWC, 128 B/pixel)
// ---------------------------------------------------------------------------
__global__ __launch_bounds__(256) void transpose_x_kernel(
    const float* __restrict__ x, unsigned short* __restrict__ xt) {
    __shared__ unsigned short t[64 * LSTR];
    int tid = threadIdx.x, bid = blockIdx.x;
    int b = bid >> 8;
    int pxbase = (bid & 255) * 64;
    int lane = tid & 63, wv = tid >> 6;
    const float* xb = x + (size_t)b * CH * HWSZ + pxbase;
#pragma unroll
    for (int i = 0; i < 16; ++i) {
        int c = wv * 16 + i;
        t[lane * LSTR + c] = f2bf(xb[(size_t)c * HWSZ + lane]);
    }
    __syncthreads();
    int px = tid >> 2, cp = (tid & 3) * 16;
    uint4 q0 = *(const uint4*)&t[px * LSTR + cp];
    uint4 q1 = *(const uint4*)&t[px * LSTR + cp + 8];
    unsigned short* o = xt + (size_t)(b * HWSZ + pxbase + px) * 64 + cp;
    *(uint4*)o = q0;
    *(uint4*)(o + 8) = q1;
}

// ---------------------------------------------------------------------------
// Kernel 2: offset conv as bf16 MFMA GEMM, B-fragments read DIRECTLY from
// NHWC global in MFMA layout (no LDS, no barriers). Tile 32co x 64px.
// ---------------------------------------------------------------------------
__global__ __launch_bounds__(256) void offset_conv_mfma(
    const unsigned short* __restrict__ xt, const unsigned short* __restrict__ wobf,
    const float* __restrict__ b_off,
    float* __restrict__ opy, float* __restrict__ opx, float* __restrict__ opm) {
    int tid = threadIdx.x, bid = blockIdx.x;
    int b = bid & 7;
    int pxbase = (bid >> 3) * 64;
    int lane = tid & 63, wv = tid >> 6;
    int quad = lane >> 4, n16 = lane & 15;
    int coh = (wv & 1) * 16;
    int pxh = (wv >> 1) * 32;

    const unsigned short* xb = xt + (size_t)b * HWSZ * 64;

    int pix2[2], ho2[2], wo2[2];
#pragma unroll
    for (int pt = 0; pt < 2; ++pt) {
        pix2[pt] = pxbase + pxh + pt * 16 + n16;
        ho2[pt] = pix2[pt] >> 7;
        wo2[pt] = pix2[pt] & (WW - 1);
    }

    f32x4 acc[2] = {{0, 0, 0, 0}, {0, 0, 0, 0}};

    for (int k = 0; k < KTAPS; ++k) {
        int ky = k / 3, kx = k - ky * 3;
        int idxp[2]; bool vp[2];
#pragma unroll
        for (int pt = 0; pt < 2; ++pt) {
            int yy = ho2[pt] + ky - 1, xx = wo2[pt] + kx - 1;
            vp[pt] = (yy >= 0) & (yy < HH) & (xx >= 0) & (xx < WW);
            idxp[pt] = vp[pt] ? (yy * WW + xx) : 0;
        }
#pragma unroll
        for (int h = 0; h < 2; ++h) {
            short8 afrag = *(const short8*)(wobf + (coh + n16) * KDIM + k * 64 + h * 32 + quad * 8);
#pragma unroll
            for (int pt = 0; pt < 2; ++pt) {
                short8 bfrag = *(const short8*)(xb + (size_t)idxp[pt] * 64 + h * 32 + quad * 8);
                if (!vp[pt]) bfrag = (short8)0;
                acc[pt] = __builtin_amdgcn_mfma_f32_16x16x32_bf16(afrag, bfrag,
                                                                  acc[pt], 0, 0, 0);
            }
        }
    }

    // Epilogue: om rows 0..8=oy, 9..17=ox, 18..26=mask
#pragma unroll
    for (int pt = 0; pt < 2; ++pt) {
#pragma unroll
        for (int r = 0; r < 4; ++r) {
            int co = coh + quad * 4 + r;
            if (co >= 27) continue;
            float val = acc[pt][r] + b_off[co];
            if (co < 9) {
                int t = co;
                opy[((b * KTAPS + t) * HWSZ) + pix2[pt]] = val + (float)(ho2[pt] - 1 + t / 3);
            } else if (co < 18) {
                int t = co - 9;
                opx[((b * KTAPS + t) * HWSZ) + pix2[pt]] = val + (float)(wo2[pt] - 1 + t % 3);
            } else {
                int t = co - 18;
                opm[((b * KTAPS + t) * HWSZ) + pix2[pt]] = 1.f / (1.f + expf(-val));
            }
        }
    }
}

// ---------------------------------------------------------------------------
// Kernel 3: deformable col build + bf16 MFMA GEMM.
// Staging lane map: lane = (px 0..7)*8 + (ch-chunk 0..7): corner loads cover
// 8 px x 16 B contiguous -> 8 lines/instr instead of 64.
// ---------------------------------------------------------------------------
__global__ __launch_bounds__(256) void dcn_main_mfma(
    const unsigned short* __restrict__ xt, const unsigned short* __restrict__ wbf,
    const float* __restrict__ b_dcn, const float* __restrict__ opy,
    const float* __restrict__ opx, const float* __restrict__ opm,
    float* __restrict__ out) {
    __shared__ unsigned short colL[64 * LSTR];

    int tid = threadIdx.x, bid = blockIdx.x;
    int b = bid & 7;
    int pxbase = (bid >> 3) * 64;
    int lane = tid & 63, wv = tid >> 6;
    int quad = lane >> 4, n16 = lane & 15;
    int h8 = lane & 7, p8 = lane >> 3;   // staging: ch-chunk, px-within-pass

    const unsigned short* xb = xt + (size_t)b * HWSZ * 64;

    f32x4 acc[4] = {{0, 0, 0, 0}, {0, 0, 0, 0}, {0, 0, 0, 0}, {0, 0, 0, 0}};

    for (int k = 0; k < KTAPS; ++k) {
        uint4 outv[2];
        int pls[2];
#pragma unroll
        for (int s = 0; s < 2; ++s) {
            int pl = wv * 16 + s * 8 + p8;   // px_local 0..63
            pls[s] = pl;
            int o = ((b * KTAPS + k) * HWSZ) + pxbase + pl;
            float fy = opy[o], fx = opx[o], m = opm[o];
            float y0f = floorf(fy), x0f = floorf(fx);
            float dy = fy - y0f, dx = fx - x0f;
            int y0 = (int)y0f, x0i = (int)x0f;
            int y1 = y0 + 1, x1 = x0i + 1;
            bool vy0 = (y0 >= 0) & (y0 < HH);
            bool vy1 = (y1 >= 0) & (y1 < HH);
            bool vx0 = (x0i >= 0) & (x0i < WW);
            bool vx1 = (x1 >= 0) & (x1 < WW);
            float w00 = (1.f - dy) * (1.f - dx) * m; if (!(vy0 && vx0)) w00 = 0.f;
            float w01 = (1.f - dy) * dx * m;         if (!(vy0 && vx1)) w01 = 0.f;
            float w10 = dy * (1.f - dx) * m;         if (!(vy1 && vx0)) w10 = 0.f;
            float w11 = dy * dx * m;                 if (!(vy1 && vx1)) w11 = 0.f;
            int yc0 = min(max(y0, 0), HH - 1), yc1 = min(max(y1, 0), HH - 1);
            int xc0 = min(max(x0i, 0), WW - 1), xc1 = min(max(x1, 0), WW - 1);
            int i00 = yc0 * WW + xc0, i01 = yc0 * WW + xc1;
            int i10 = yc1 * WW + xc0, i11 = yc1 * WW + xc1;

            // 8 channels (16 B) per corner for this lane's ch-chunk
            uint4 qa = *(const uint4*)(xb + (size_t)i00 * 64 + h8 * 8);
            uint4 qb = *(const uint4*)(xb + (size_t)i01 * 64 + h8 * 8);
            uint4 qc = *(const uint4*)(xb + (size_t)i10 * 64 + h8 * 8);
            uint4 qd = *(const uint4*)(xb + (size_t)i11 * 64 + h8 * 8);

            uint4 r;
            r.x = bilin2(qa.x, qb.x, qc.x, qd.x, w00, w01, w10, w11);
            r.y = bilin2(qa.y, qb.y, qc.y, qd.y, w00, w01, w10, w11);
            r.z = bilin2(qa.z, qb.z, qc.z, qd.z, w00, w01, w10, w11);
            r.w = bilin2(qa.w, qb.w, qc.w, qd.w, w00, w01, w10, w11);
            outv[s] = r;
        }

        __syncthreads();
        *(uint4*)&colL[pls[0] * LSTR + h8 * 8] = outv[0];
        *(uint4*)&colL[pls[1] * LSTR + h8 * 8] = outv[1];
        __syncthreads();

        int co = wv * 16 + n16;
#pragma unroll
        for (int h = 0; h < 2; ++h) {
            short8 afrag = *(const short8*)(wbf + co * KDIM + k * 64 + h * 32 + quad * 8);
#pragma unroll
            for (int pt = 0; pt < 4; ++pt) {
                short8 bfrag = *(const short8*)(&colL[(pt * 16 + n16) * LSTR + h * 32 + quad * 8]);
                acc[pt] = __builtin_amdgcn_mfma_f32_16x16x32_bf16(afrag, bfrag,
                                                                  acc[pt], 0, 0, 0);
            }
        }
    }

    // Epilogue: D[m = quad*4+r][n = lane&15], co = wv*16 + m
    float* ob = out + (size_t)b * COUT * HWSZ;
#pragma unroll
    for (int pt = 0; pt < 4; ++pt) {
        int px = pxbase + pt * 16 + n16;
#pragma unroll
        for (int r = 0; r < 4; ++r) {
            int co = wv * 16 + quad * 4 + r;
            ob[(size_t)co * HWSZ + px] = acc[pt][r] + b_dcn[co];
        }
    }
}

// ---------------------------------------------------------------------------
extern "C" void kernel_launch(void* const* d_in, const int* in_sizes, int n_in,
                              void* d_out, int out_size, void* d_ws, size_t ws_size,
                              hipStream_t stream) {
    const float* x     = (const float*)d_in[0];
    const float* w_off = (const float*)d_in[1];
    const float* b_off = (const float*)d_in[2];
    const float* w_dcn = (const float*)d_in[3];
    const float* b_dcn = (const float*)d_in[4];
    float* out = (float*)d_out;

    // ws layout: xt (bf16 NHWC) | opy | opx | opm (fp32) | wbf | wobf (bf16)
    const int NOFF = BATCH * KTAPS * HWSZ;           // 1,179,648 floats
    unsigned short* xt = (unsigned short*)d_ws;      // 8,388,608 ushorts
    float* opy = (float*)(xt + (size_t)BATCH * HWSZ * 64);
    float* opx = opy + NOFF;
    float* opm = opx + NOFF;
    unsigned short* wbf  = (unsigned short*)(opm + NOFF);
    unsigned short* wobf = wbf + COUT * KDIM;

    hipLaunchKernelGGL(prep_w_kernel, dim3(216), dim3(256), 0, stream,
                       w_dcn, w_off, wbf, wobf);
    hipLaunchKernelGGL(transpose_x_kernel, dim3(2048), dim3(256), 0, stream, x, xt);
    hipLaunchKernelGGL(offset_conv_mfma, dim3(BATCH * HWSZ / 64), dim3(256),
                       0, stream, xt, wobf, b_off, opy, opx, opm);
    hipLaunchKernelGGL(dcn_main_mfma, dim3(BATCH * HWSZ / 64), dim3(256),
                       0, stream, xt, wbf, b_dcn, opy, opx, opm, out);
}

// Round 5
// 175.287 us; speedup vs baseline: 2.1311x; 1.0815x over previous
//
#include <hip/hip_runtime.h>
#include <math.h>

#define BATCH 8
#define CH    64
#define HH    128
#define WW    128
#define HWSZ  (HH * WW)       // 16384
#define COUT  64
#define KTAPS 9
#define KDIM  576             // CH * KTAPS
#define LSTR  72              // ushorts per LDS px-row (144 B)

typedef __attribute__((ext_vector_type(8))) short short8;
typedef __attribute__((ext_vector_type(4))) float f32x4;

__device__ __forceinline__ unsigned short f2bf(float f) {
    unsigned int u = __float_as_uint(f);
    u += 0x7fffu + ((u >> 16) & 1u);
    return (unsigned short)(u >> 16);
}
__device__ __forceinline__ float bflo(unsigned int u) { return __uint_as_float(u << 16); }
__device__ __forceinline__ float bfhi(unsigned int u) { return __uint_as_float(u & 0xffff0000u); }

// bilinear-combine one dword (2 bf16 channels) from 4 corners; pack via v_perm
__device__ __forceinline__ unsigned int bilin2(unsigned int a, unsigned int b,
                                               unsigned int c, unsigned int d,
                                               float w00, float w01, float w10, float w11) {
    float lo = w00 * bflo(a);
    lo = fmaf(w01, bflo(b), lo);
    lo = fmaf(w10, bflo(c), lo);
    lo = fmaf(w11, bflo(d), lo);
    float hi = w00 * bfhi(a);
    hi = fmaf(w01, bfhi(b), hi);
    hi = fmaf(w10, bfhi(c), hi);
    hi = fmaf(w11, bfhi(d), hi);
    // round-half-up then take top16 of each: D = {hi[3],hi[2],lo[3],lo[2]}
    return __builtin_amdgcn_perm(__float_as_uint(hi) + 0x8000u,
                                 __float_as_uint(lo) + 0x8000u, 0x07060302u);
}

// ---------------------------------------------------------------------------
// Kernel 0: NCHW fp32 -> NHWC bf16 transpose; blocks < 216 also convert the
// conv weights into MFMA-friendly bf16 layouts.
//  wbf [co][ck=k*64+c] (64 x 576), wobf[co][ck=k*64+c] (32 x 576, rows>=27 =0)
// ---------------------------------------------------------------------------
__global__ __launch_bounds__(256) void transpose_x_kernel(
    const float* __restrict__ x, unsigned short* __restrict__ xt,
    const float* __restrict__ w_dcn, const float* __restrict__ w_off,
    unsigned short* __restrict__ wbf, unsigned short* __restrict__ wobf) {
    __shared__ unsigned short t[64 * LSTR];
    int tid = threadIdx.x, bid = blockIdx.x;

    if (bid < 216) {  // weight prep: 216*256 = 55296 elements
        int j = bid * 256 + tid;
        const int N1 = COUT * KDIM;      // 36864
        if (j < N1) {
            int co = j / KDIM;
            int ck = j - co * KDIM;
            int k = ck >> 6, c = ck & 63;
            wbf[j] = f2bf(w_dcn[(co * CH + c) * KTAPS + k]);
        } else {
            int jj = j - N1;
            int co = jj / KDIM;
            int ck = jj - co * KDIM;
            int k = ck >> 6, c = ck & 63;
            wobf[jj] = (co < 27) ? f2bf(w_off[(co * CH + c) * KTAPS + k]) : 0;
        }
    }

    int b = bid >> 8;
    int pxbase = (bid & 255) * 64;
    int lane = tid & 63, wv = tid >> 6;
    const float* xb = x + (size_t)b * CH * HWSZ + pxbase;
#pragma unroll
    for (int i = 0; i < 16; ++i) {
        int c = wv * 16 + i;
        t[lane * LSTR + c] = f2bf(xb[(size_t)c * HWSZ + lane]);
    }
    __syncthreads();
    int px = tid >> 2, cp = (tid & 3) * 16;
    uint4 q0 = *(const uint4*)&t[px * LSTR + cp];
    uint4 q1 = *(const uint4*)&t[px * LSTR + cp + 8];
    unsigned short* o = xt + (size_t)(b * HWSZ + pxbase + px) * 64 + cp;
    *(uint4*)o = q0;
    *(uint4*)(o + 8) = q1;
}

// ---------------------------------------------------------------------------
// Kernel 1: FUSED offset-conv + deformable col build + main MFMA GEMM.
// Per block: 64-px tile.
//  Phase 1: offset GEMM 32co x 64px, direct NHWC B-frags -> omr[27][64] LDS.
//  Phase 2: per (tap,px): bilinear params -> wgt (float4) + idx (ushort4) LDS.
//  Phase 3: per tap: gather 4 corners (8ch/lane), combine, colL, MFMA.
// LDS: union(omr 6912 B, colL 9216 B) @0 | wgt 9216 B @9216 | idx 4608 B @18432
// ---------------------------------------------------------------------------
__global__ __launch_bounds__(256, 4) void dcn_fused_mfma(
    const unsigned short* __restrict__ xt, const unsigned short* __restrict__ wbf,
    const unsigned short* __restrict__ wobf, const float* __restrict__ b_off,
    const float* __restrict__ b_dcn, float* __restrict__ out) {
    __shared__ __align__(16) unsigned char smem[23040];
    unsigned short* colL = (unsigned short*)smem;        // phase 3
    float* omr = (float*)smem;                           // phases 1-2 (union)
    float4* wgt = (float4*)(smem + 9216);
    ushort4* idxA = (ushort4*)(smem + 18432);

    int tid = threadIdx.x, bid = blockIdx.x;
    int b = bid & 7;                 // batch -> XCD pinning
    int pxbase = (bid >> 3) * 64;
    int lane = tid & 63, wv = tid >> 6;
    int quad = lane >> 4, n16 = lane & 15;
    int h8 = lane & 7, p8 = lane >> 3;

    const unsigned short* xb = xt + (size_t)b * HWSZ * 64;

    // ---------------- Phase 1: offset conv GEMM -> omr ----------------
    {
        int coh = (wv & 1) * 16;
        int pxh = (wv >> 1) * 32;
        int pixL[2], oho[2], owo[2];
#pragma unroll
        for (int pt = 0; pt < 2; ++pt) {
            pixL[pt] = pxh + pt * 16 + n16;
            int pix = pxbase + pixL[pt];
            oho[pt] = pix >> 7;
            owo[pt] = pix & (WW - 1);
        }
        f32x4 oacc[2] = {{0, 0, 0, 0}, {0, 0, 0, 0}};
        for (int k = 0; k < KTAPS; ++k) {
            int ky = k / 3, kx = k - ky * 3;
            int idxp[2]; bool vp[2];
#pragma unroll
            for (int pt = 0; pt < 2; ++pt) {
                int yy = oho[pt] + ky - 1, xx = owo[pt] + kx - 1;
                vp[pt] = (yy >= 0) & (yy < HH) & (xx >= 0) & (xx < WW);
                idxp[pt] = vp[pt] ? (yy * WW + xx) : 0;
            }
#pragma unroll
            for (int h = 0; h < 2; ++h) {
                short8 afrag = *(const short8*)(wobf + (coh + n16) * KDIM + k * 64 + h * 32 + quad * 8);
#pragma unroll
                for (int pt = 0; pt < 2; ++pt) {
                    short8 bfrag = *(const short8*)(xb + (size_t)idxp[pt] * 64 + h * 32 + quad * 8);
                    if (!vp[pt]) bfrag = (short8)0;
                    oacc[pt] = __builtin_amdgcn_mfma_f32_16x16x32_bf16(afrag, bfrag,
                                                                       oacc[pt], 0, 0, 0);
                }
            }
        }
#pragma unroll
        for (int pt = 0; pt < 2; ++pt) {
#pragma unroll
            for (int r = 0; r < 4; ++r) {
                int co = coh + quad * 4 + r;
                if (co < 27) omr[co * 64 + pixL[pt]] = oacc[pt][r] + b_off[co];
            }
        }
    }
    __syncthreads();

    // ---------------- Phase 2: bilinear params -> wgt/idx ----------------
    for (int j = tid; j < KTAPS * 64; j += 256) {
        int tap = j >> 6, pl = j & 63;
        int pix = pxbase + pl, ho = pix >> 7, wo = pix & (WW - 1);
        float fy = omr[tap * 64 + pl] + (float)(ho - 1 + tap / 3);
        float fx = omr[(9 + tap) * 64 + pl] + (float)(wo - 1 + tap % 3);
        float m = 1.f / (1.f + __expf(-omr[(18 + tap) * 64 + pl]));
        float y0f = floorf(fy), x0f = floorf(fx);
        float dy = fy - y0f, dx = fx - x0f;
        int y0 = (int)y0f, x0i = (int)x0f;
        int y1 = y0 + 1, x1 = x0i + 1;
        bool vy0 = (y0 >= 0) & (y0 < HH);
        bool vy1 = (y1 >= 0) & (y1 < HH);
        bool vx0 = (x0i >= 0) & (x0i < WW);
        bool vx1 = (x1 >= 0) & (x1 < WW);
        float w00 = (1.f - dy) * (1.f - dx) * m; if (!(vy0 && vx0)) w00 = 0.f;
        float w01 = (1.f - dy) * dx * m;         if (!(vy0 && vx1)) w01 = 0.f;
        float w10 = dy * (1.f - dx) * m;         if (!(vy1 && vx0)) w10 = 0.f;
        float w11 = dy * dx * m;                 if (!(vy1 && vx1)) w11 = 0.f;
        int yc0 = min(max(y0, 0), HH - 1), yc1 = min(max(y1, 0), HH - 1);
        int xc0 = min(max(x0i, 0), WW - 1), xc1 = min(max(x1, 0), WW - 1);
        wgt[j] = make_float4(w00, w01, w10, w11);
        idxA[j] = make_ushort4((unsigned short)(yc0 * WW + xc0),
                               (unsigned short)(yc0 * WW + xc1),
                               (unsigned short)(yc1 * WW + xc0),
                               (unsigned short)(yc1 * WW + xc1));
    }
    __syncthreads();   // params visible; omr dead from here

    // ---------------- Phase 3: col build + main GEMM ----------------
    f32x4 acc[4] = {{0, 0, 0, 0}, {0, 0, 0, 0}, {0, 0, 0, 0}, {0, 0, 0, 0}};

    for (int k = 0; k < KTAPS; ++k) {
        uint4 outv[2];
        int pls[2];
#pragma unroll
        for (int s = 0; s < 2; ++s) {
            int pl = wv * 16 + s * 8 + p8;
            pls[s] = pl;
            float4 w4 = wgt[k * 64 + pl];
            ushort4 i4 = idxA[k * 64 + pl];
            uint4 qa = *(const uint4*)(xb + (size_t)i4.x * 64 + h8 * 8);
            uint4 qb = *(const uint4*)(xb + (size_t)i4.y * 64 + h8 * 8);
            uint4 qc = *(const uint4*)(xb + (size_t)i4.z * 64 + h8 * 8);
            uint4 qd = *(const uint4*)(xb + (size_t)i4.w * 64 + h8 * 8);
            uint4 r;
            r.x = bilin2(qa.x, qb.x, qc.x, qd.x, w4.x, w4.y, w4.z, w4.w);
            r.y = bilin2(qa.y, qb.y, qc.y, qd.y, w4.x, w4.y, w4.z, w4.w);
            r.z = bilin2(qa.z, qb.z, qc.z, qd.z, w4.x, w4.y, w4.z, w4.w);
            r.w = bilin2(qa.w, qb.w, qc.w, qd.w, w4.x, w4.y, w4.z, w4.w);
            outv[s] = r;
        }

        __syncthreads();
        *(uint4*)&colL[pls[0] * LSTR + h8 * 8] = outv[0];
        *(uint4*)&colL[pls[1] * LSTR + h8 * 8] = outv[1];
        __syncthreads();

        int co = wv * 16 + n16;
#pragma unroll
        for (int h = 0; h < 2; ++h) {
            short8 afrag = *(const short8*)(wbf + co * KDIM + k * 64 + h * 32 + quad * 8);
#pragma unroll
            for (int pt = 0; pt < 4; ++pt) {
                short8 bfrag = *(const short8*)(&colL[(pt * 16 + n16) * LSTR + h * 32 + quad * 8]);
                acc[pt] = __builtin_amdgcn_mfma_f32_16x16x32_bf16(afrag, bfrag,
                                                                  acc[pt], 0, 0, 0);
            }
        }
    }

    // Epilogue: D[m = quad*4+r][n = lane&15], co = wv*16 + m
    float* ob = out + (size_t)b * COUT * HWSZ;
#pragma unroll
    for (int pt = 0; pt < 4; ++pt) {
        int px = pxbase + pt * 16 + n16;
#pragma unroll
        for (int r = 0; r < 4; ++r) {
            int co = wv * 16 + quad * 4 + r;
            ob[(size_t)co * HWSZ + px] = acc[pt][r] + b_dcn[co];
        }
    }
}

// ---------------------------------------------------------------------------
extern "C" void kernel_launch(void* const* d_in, const int* in_sizes, int n_in,
                              void* d_out, int out_size, void* d_ws, size_t ws_size,
                              hipStream_t stream) {
    const float* x     = (const float*)d_in[0];
    const float* w_off = (const float*)d_in[1];
    const float* b_off = (const float*)d_in[2];
    const float* w_dcn = (const float*)d_in[3];
    const float* b_dcn = (const float*)d_in[4];
    float* out = (float*)d_out;

    // ws layout: xt (bf16 NHWC) | wbf | wobf
    unsigned short* xt   = (unsigned short*)d_ws;            // 8,388,608 ushorts
    unsigned short* wbf  = xt + (size_t)BATCH * HWSZ * 64;
    unsigned short* wobf = wbf + COUT * KDIM;

    hipLaunchKernelGGL(transpose_x_kernel, dim3(2048), dim3(256), 0, stream,
                       x, xt, w_dcn, w_off, wbf, wobf);
    hipLaunchKernelGGL(dcn_fused_mfma, dim3(BATCH * HWSZ / 64), dim3(256),
                       0, stream, xt, wbf, wobf, b_off, b_dcn, out);
}